// Round 2
// baseline (697.651 us; speedup 1.0000x reference)
//
#include <hip/hip_runtime.h>
#include <cstdint>

#define EPS 1e-5f

typedef unsigned long long u64;
typedef unsigned int u32;
typedef unsigned short u16;
typedef unsigned char u8;

__device__ __forceinline__ int clampi(int v, int lo, int hi) {
    return v < lo ? lo : (v > hi ? hi : v);
}

// ======================= unit bodies (identical math to the 208us baseline) =======================

__device__ __forceinline__ void prep_small_body(
    int t,
    const float* __restrict__ conv1_w, const float* __restrict__ conv2_w,
    const float* __restrict__ fc2_w,
    const float* __restrict__ g1, const float* __restrict__ b1,
    const float* __restrict__ m1, const float* __restrict__ v1,
    const float* __restrict__ g2, const float* __restrict__ b2,
    const float* __restrict__ m2, const float* __restrict__ v2,
    float* __restrict__ s1, u64* __restrict__ w2p, u64* __restrict__ w2pk,
    float4* __restrict__ bnc1, float4* __restrict__ bnc2)
{
    if (t < 576) {
        s1[t] = (conv1_w[t] >= 0.f) ? 1.f : -1.f;
    } else if (t < 1152) {
        int u = t - 576;
        int co = u / 9, tap = u % 9;
        u64 word = 0;
        for (int ci = 0; ci < 64; ci++)
            word |= (u64)(conv2_w[(co * 64 + ci) * 9 + tap] >= 0.f) << ci;
        w2p[u] = word;
    } else if (t < 1472) {
        int u = t - 1152;
        int o = u / 32, k = u % 32;
        u64 word = 0;
        for (int j = 0; j < 64; j++)
            word |= (u64)(fc2_w[o * 2048 + k * 64 + j] >= 0.f) << j;
        w2pk[u] = word;
    } else if (t < 1536) {
        int ch = t - 1472;
        bnc1[ch] = make_float4(m1[ch], g1[ch] / sqrtf(v1[ch] + EPS), b1[ch], 0.f);
    } else if (t < 1600) {
        int ch = t - 1536;
        bnc2[ch] = make_float4(m2[ch], g2[ch] / sqrtf(v2[ch] + EPS), b2[ch], 0.f);
    }
}

// fc1_w [2048,3136] (flat idx = c*49+p) -> wp[p*2048+o], bit c
__device__ __forceinline__ void prep_fc1_body(
    int o, float* ls,
    const float* __restrict__ w, u64* __restrict__ wp)
{
    const float4* row4 = (const float4*)(w + o * 3136);
    for (int i = threadIdx.x; i < 784; i += 256)
        ((float4*)ls)[i] = row4[i];
    __syncthreads();
    int p = threadIdx.x;
    if (p < 49) {
        u64 word = 0;
        #pragma unroll
        for (int c = 0; c < 64; c++)
            word |= (u64)(ls[c * 49 + p] >= 0.f) << c;
        wp[p * 2048 + o] = word;
    }
    __syncthreads();   // ls reused by the next grid-stride unit
}

// conv1 + bn1 + sign + maxpool -> packed [B,14,14]; 16 channels per call (g in 0..3)
__device__ __forceinline__ void conv1_body(
    int idx, int g,
    const float* __restrict__ x, const float* __restrict__ s1,
    const float4* __restrict__ bnc1, u64* __restrict__ out1)
{
    int base = g * 16;
    int b = idx / 196, p = idx % 196;
    int pi = p / 14, pj = p % 14;

    const float* xb = x + b * 784;
    int rr[4], cc[4];
    #pragma unroll
    for (int r = 0; r < 4; r++) rr[r] = clampi(2 * pi - 1 + r, 0, 27) * 28;
    #pragma unroll
    for (int c = 0; c < 4; c++) cc[c] = clampi(2 * pj - 1 + c, 0, 27);
    float patch[4][4];
    #pragma unroll
    for (int r = 0; r < 4; r++)
        #pragma unroll
        for (int c = 0; c < 4; c++)
            patch[r][c] = xb[rr[r] + cc[c]];

    u32 word = 0;
    #pragma unroll 4
    for (int ch = 0; ch < 16; ch++) {
        const float* w = s1 + (base + ch) * 9;  // wave-uniform -> s_load
        float v00 = 0.f, v01 = 0.f, v10 = 0.f, v11 = 0.f;
        #pragma unroll
        for (int ki = 0; ki < 3; ki++)
            #pragma unroll
            for (int kj = 0; kj < 3; kj++) {
                float ww = w[ki * 3 + kj];
                v00 += patch[ki][kj] * ww;
                v01 += patch[ki][kj + 1] * ww;
                v10 += patch[ki + 1][kj] * ww;
                v11 += patch[ki + 1][kj + 1] * ww;
            }
        float vmin = fminf(fminf(v00, v01), fminf(v10, v11));
        float vmax = fmaxf(fmaxf(v00, v01), fmaxf(v10, v11));
        float4 c4 = bnc1[base + ch];            // wave-uniform -> s_load_dwordx4
        int bit = (((vmin - c4.x) * c4.y + c4.z) >= 0.f) |
                  (((vmax - c4.x) * c4.y + c4.z) >= 0.f);
        word |= (u32)bit << ch;
    }
    ((u16*)out1)[idx * 4 + g] = (u16)word;      // little-endian u64 quarters
}

// conv2 + bn2 + sign + maxpool -> packed [B,7,7]; 8 out-channels per call (g in 0..7)
__device__ __forceinline__ void conv2_body(
    int idx, int g,
    const u64* __restrict__ in, const u64* __restrict__ w2p,
    const float4* __restrict__ bnc2, u64* __restrict__ out2)
{
    int base = g * 8;
    int b = idx / 49, p = idx % 49;
    int pi = p / 7, pj = p % 7;

    const u64* ib = in + b * 196;
    int rr[4], cc[4];
    #pragma unroll
    for (int r = 0; r < 4; r++) rr[r] = clampi(2 * pi - 1 + r, 0, 13) * 14;
    #pragma unroll
    for (int c = 0; c < 4; c++) cc[c] = clampi(2 * pj - 1 + c, 0, 13);
    u64 a[4][4];
    #pragma unroll
    for (int r = 0; r < 4; r++)
        #pragma unroll
        for (int c = 0; c < 4; c++)
            a[r][c] = ib[rr[r] + cc[c]];

    u32 word = 0;
    #pragma unroll
    for (int co = 0; co < 8; co++) {
        const u64* w = w2p + (base + co) * 9;   // wave-uniform -> s_load
        int s00 = 0, s01 = 0, s10 = 0, s11 = 0;
        #pragma unroll
        for (int ki = 0; ki < 3; ki++)
            #pragma unroll
            for (int kj = 0; kj < 3; kj++) {
                u64 ww = w[ki * 3 + kj];
                s00 += __popcll(a[ki][kj] ^ ww);
                s01 += __popcll(a[ki][kj + 1] ^ ww);
                s10 += __popcll(a[ki + 1][kj] ^ ww);
                s11 += __popcll(a[ki + 1][kj + 1] ^ ww);
            }
        int smin = min(min(s00, s01), min(s10, s11));
        int smax = max(max(s00, s01), max(s10, s11));
        float4 c4 = bnc2[base + co];
        int bit = (((float)(576 - 2 * smin) - c4.x) * c4.y + c4.z >= 0.f) |
                  (((float)(576 - 2 * smax) - c4.x) * c4.y + c4.z >= 0.f);
        word |= (u32)bit << co;
    }
    ((u8*)out2)[idx * 8 + g] = (u8)word;        // little-endian u64 bytes
}

#define NB 8

// fc1 + bn3 + sign -> packed [B,32]; one unit = 256 outputs x NB batches
__device__ __forceinline__ void fc1_body(
    int u, int tid,
    const u64* __restrict__ act, const u64* __restrict__ wp,
    const float* __restrict__ g, const float* __restrict__ bt,
    const float* __restrict__ mn, const float* __restrict__ vr,
    u64* __restrict__ out3)
{
    int btile = u >> 3;
    int otile = u & 7;
    int b0 = btile * NB;
    int o = otile * 256 + tid;
    const u64* ab = act + b0 * 49;

    int sums[NB];
    #pragma unroll
    for (int i = 0; i < NB; i++) sums[i] = 0;

    for (int p = 0; p < 49; p++) {
        u64 w = wp[p * 2048 + o];
        #pragma unroll
        for (int bb = 0; bb < NB; bb++)
            sums[bb] += __popcll(ab[bb * 49 + p] ^ w);   // ab idx uniform -> s_load
    }

    float iv = g[o] / sqrtf(vr[o] + EPS);
    float m = mn[o], be = bt[o];
    #pragma unroll
    for (int bb = 0; bb < NB; bb++) {
        float y = ((float)(3136 - 2 * sums[bb]) - m) * iv + be;
        u64 ball = __ballot(y >= 0.f);
        if ((tid & 63) == 0) out3[(b0 + bb) * 32 + (o >> 6)] = ball;
    }
}

__device__ __forceinline__ void fc2_body(
    int idx,
    const u64* __restrict__ act, const u64* __restrict__ w2,
    const float* __restrict__ scale, float* __restrict__ out)
{
    if (idx >= 2048 * 16) return;
    int b = idx >> 4, o = idx & 15;
    if (o >= 10) return;
    int s = 0;
    #pragma unroll
    for (int k = 0; k < 32; k++)
        s += __popcll(act[b * 32 + k] ^ w2[o * 32 + k]);
    out[b * 10 + o] = scale[0] * (float)(2048 - 2 * s);
}

// ======================= manual grid barrier (co-resident persistent kernel) =======================
// Monotone counter, zeroed by a captured hipMemsetAsync each replay.
// AGENT-scope atomics give cross-XCD release/acquire (buffer_wbl2 / buffer_inv).
// Bounded spin: if co-residency were ever violated we produce a wrong answer,
// never a hang (no container kill).

__device__ __forceinline__ void gbar(u32* cnt, u32 target) {
    __syncthreads();                         // drains this block's vmem (vmcnt 0)
    if (threadIdx.x == 0) {
        __threadfence();                     // agent release fence (L2 writeback)
        __hip_atomic_fetch_add(cnt, 1u, __ATOMIC_RELEASE, __HIP_MEMORY_SCOPE_AGENT);
        u32 guard = 0;
        while (__hip_atomic_load(cnt, __ATOMIC_ACQUIRE, __HIP_MEMORY_SCOPE_AGENT) < target) {
            __builtin_amdgcn_s_sleep(8);
            if (++guard > (1u << 18)) break; // ~50ms hang guard; never hit when co-resident
        }
        __threadfence();                     // agent acquire fence (invalidate stale lines)
    }
    __syncthreads();
}

// ======================= fused persistent kernel =======================

struct FusedArgs {
    const float *x, *conv1_w, *conv2_w, *fc2_w;
    const float *g1, *b1, *m1, *v1;
    const float *g2, *b2, *m2, *v2;
    const float *fc1_w;
    const float *g3, *b3, *m3, *v3;
    const float *scale;
    float* out;
    float* s1; u64* w2p; u64* w2pk; float4* bnc1; float4* bnc2;
    u64* wp; u64* out1; u64* out2; u64* out3;
    u32* bar;
};

// min 2 waves/EU declared -> VGPR <= 256 -> >= 2 blocks/CU; LDS 12.5KB (not limiting).
// Grid (512 or 1024) is checked co-resident via hipOccupancy* before launch.
__global__ __launch_bounds__(256, 2) void fused_persist(FusedArgs A) {
    __shared__ float ls[3136];
    const int nb = gridDim.x, bid = blockIdx.x, tid = threadIdx.x;

    // ---- S1: fc1-weight repack (2048 units) + tiny prep (7 units) ----
    for (int u = bid; u < 2055; u += nb) {
        if (u < 2048) {
            prep_fc1_body(u, ls, A.fc1_w, A.wp);
        } else {
            prep_small_body((u - 2048) * 256 + tid, A.conv1_w, A.conv2_w, A.fc2_w,
                            A.g1, A.b1, A.m1, A.v1, A.g2, A.b2, A.m2, A.v2,
                            A.s1, A.w2p, A.w2pk, A.bnc1, A.bnc2);
        }
    }
    gbar(A.bar, (u32)nb);

    // ---- S2: conv1 (6272 units) ----
    for (int u = bid; u < 6272; u += nb)
        conv1_body((u % 1568) * 256 + tid, u / 1568, A.x, A.s1, A.bnc1, A.out1);
    gbar(A.bar, (u32)(2 * nb));

    // ---- S3: conv2 (3136 units) ----
    for (int u = bid; u < 3136; u += nb)
        conv2_body((u % 392) * 256 + tid, u / 392, A.out1, A.w2p, A.bnc2, A.out2);
    gbar(A.bar, (u32)(3 * nb));

    // ---- S4: fc1 (2048 units) ----
    for (int u = bid; u < 2048; u += nb)
        fc1_body(u, tid, A.out2, A.wp, A.g3, A.b3, A.m3, A.v3, A.out3);
    gbar(A.bar, (u32)(4 * nb));

    // ---- S5: fc2 (128 units) ----
    for (int u = bid; u < 128; u += nb)
        fc2_body(u * 256 + tid, A.out3, A.w2pk, A.scale, A.out);
}

// ======================= fallback standalone kernels (proven baseline path) =======================

__global__ void prep_small(
    const float* __restrict__ conv1_w, const float* __restrict__ conv2_w,
    const float* __restrict__ fc2_w,
    const float* __restrict__ g1, const float* __restrict__ b1,
    const float* __restrict__ m1, const float* __restrict__ v1,
    const float* __restrict__ g2, const float* __restrict__ b2,
    const float* __restrict__ m2, const float* __restrict__ v2,
    float* __restrict__ s1, u64* __restrict__ w2p, u64* __restrict__ w2pk,
    float4* __restrict__ bnc1, float4* __restrict__ bnc2)
{
    prep_small_body(blockIdx.x * 256 + threadIdx.x, conv1_w, conv2_w, fc2_w,
                    g1, b1, m1, v1, g2, b2, m2, v2, s1, w2p, w2pk, bnc1, bnc2);
}

__global__ __launch_bounds__(256) void prep_fc1(const float* __restrict__ w,
                                                u64* __restrict__ wp) {
    __shared__ float ls[3136];
    prep_fc1_body(blockIdx.x, ls, w, wp);
}

__global__ __launch_bounds__(256) void k_conv1(
    const float* __restrict__ x, const float* __restrict__ s1,
    const float4* __restrict__ bnc1, u64* __restrict__ out1)
{
    conv1_body(blockIdx.x * 256 + threadIdx.x, blockIdx.y, x, s1, bnc1, out1);
}

__global__ __launch_bounds__(256) void k_conv2(
    const u64* __restrict__ in, const u64* __restrict__ w2p,
    const float4* __restrict__ bnc2, u64* __restrict__ out2)
{
    conv2_body(blockIdx.x * 256 + threadIdx.x, blockIdx.y, in, w2p, bnc2, out2);
}

__global__ __launch_bounds__(256) void k_fc1(
    const u64* __restrict__ act, const u64* __restrict__ wp,
    const float* __restrict__ g, const float* __restrict__ bt,
    const float* __restrict__ mn, const float* __restrict__ vr,
    u64* __restrict__ out3)
{
    fc1_body(blockIdx.x, threadIdx.x, act, wp, g, bt, mn, vr, out3);
}

__global__ void k_fc2(const u64* __restrict__ act, const u64* __restrict__ w2,
                      const float* __restrict__ scale, float* __restrict__ out)
{
    fc2_body(blockIdx.x * 256 + threadIdx.x, act, w2, scale, out);
}

// ======================= launch =======================

extern "C" void kernel_launch(void* const* d_in, const int* in_sizes, int n_in,
                              void* d_out, int out_size, void* d_ws, size_t ws_size,
                              hipStream_t stream) {
    const float* x        = (const float*)d_in[0];
    const float* conv1_w  = (const float*)d_in[1];
    const float* bn1_g    = (const float*)d_in[2];
    const float* bn1_b    = (const float*)d_in[3];
    const float* bn1_m    = (const float*)d_in[4];
    const float* bn1_v    = (const float*)d_in[5];
    const float* conv2_w  = (const float*)d_in[6];
    const float* bn2_g    = (const float*)d_in[7];
    const float* bn2_b    = (const float*)d_in[8];
    const float* bn2_m    = (const float*)d_in[9];
    const float* bn2_v    = (const float*)d_in[10];
    const float* fc1_w    = (const float*)d_in[11];
    const float* bn3_g    = (const float*)d_in[12];
    const float* bn3_b    = (const float*)d_in[13];
    const float* bn3_m    = (const float*)d_in[14];
    const float* bn3_v    = (const float*)d_in[15];
    const float* fc2_w    = (const float*)d_in[16];
    const float* scale    = (const float*)d_in[17];
    float* out = (float*)d_out;

    char* ws = (char*)d_ws;
    float*  s1   = (float*) (ws + 0);          //   2304 B
    u64*    w2p  = (u64*)   (ws + 2560);       //   4608 B (ends 7168)
    float4* bnc1 = (float4*)(ws + 7168);       //   1024 B (ends 8192)
    u64*    wp   = (u64*)   (ws + 8192);       // 802816 B (ends 811008)
    u64*    w2pk = (u64*)   (ws + 811008);     //   2560 B (ends 813568)
    float4* bnc2 = (float4*)(ws + 813568);     //   1024 B (ends 814592)
    u64*    out1 = (u64*)   (ws + 819200);     // 3211264 B (ends 4030464)
    u64*    out2 = (u64*)   (ws + 4030464);    // 802816 B (ends 4833280)
    u64*    out3 = (u64*)   (ws + 4833280);    // 524288 B (ends 5357568)
    u32*    bar  = (u32*)   (ws + 5357568);    //    256 B (ends 5357824)

    FusedArgs fa;
    fa.x = x; fa.conv1_w = conv1_w; fa.conv2_w = conv2_w; fa.fc2_w = fc2_w;
    fa.g1 = bn1_g; fa.b1 = bn1_b; fa.m1 = bn1_m; fa.v1 = bn1_v;
    fa.g2 = bn2_g; fa.b2 = bn2_b; fa.m2 = bn2_m; fa.v2 = bn2_v;
    fa.fc1_w = fc1_w;
    fa.g3 = bn3_g; fa.b3 = bn3_b; fa.m3 = bn3_m; fa.v3 = bn3_v;
    fa.scale = scale; fa.out = out;
    fa.s1 = s1; fa.w2p = w2p; fa.w2pk = w2pk; fa.bnc1 = bnc1; fa.bnc2 = bnc2;
    fa.wp = wp; fa.out1 = out1; fa.out2 = out2; fa.out3 = out3;
    fa.bar = bar;

    // Verify >=2 blocks/CU so grid <= 2*256 (or 4*256) is co-resident.
    static int cfg = -2;   // -2 unknown, -1 fallback, >0 grid size
    if (cfg == -2) {
        int maxb = 0;
        hipError_t e = hipOccupancyMaxActiveBlocksPerMultiprocessor(
            &maxb, (const void*)fused_persist, 256, 0);
        if (e == hipSuccess && maxb >= 2) {
            cfg = (maxb >= 4) ? 1024 : 512;
        } else {
            cfg = -1;
            (void)hipGetLastError();
        }
    }

    if (cfg > 0) {
        hipMemsetAsync(bar, 0, 256, stream);   // capture-safe node; re-inits barrier each replay
        hipLaunchKernelGGL(fused_persist, dim3(cfg), dim3(256), 0, stream, fa);
    } else {
        hipLaunchKernelGGL(prep_small, dim3(7), dim3(256), 0, stream,
                           conv1_w, conv2_w, fc2_w,
                           bn1_g, bn1_b, bn1_m, bn1_v,
                           bn2_g, bn2_b, bn2_m, bn2_v,
                           s1, w2p, w2pk, bnc1, bnc2);
        hipLaunchKernelGGL(prep_fc1, dim3(2048), dim3(256), 0, stream, fc1_w, wp);
        hipLaunchKernelGGL(k_conv1, dim3(1568, 4), dim3(256), 0, stream,
                           x, s1, bnc1, out1);
        hipLaunchKernelGGL(k_conv2, dim3(392, 8), dim3(256), 0, stream,
                           out1, w2p, bnc2, out2);
        hipLaunchKernelGGL(k_fc1, dim3(2048), dim3(256), 0, stream,
                           out2, wp, bn3_g, bn3_b, bn3_m, bn3_v, out3);
        hipLaunchKernelGGL(k_fc2, dim3(128), dim3(256), 0, stream,
                           out3, w2pk, scale, out);
    }
}

// Round 3
// 236.941 us; speedup vs baseline: 2.9444x; 2.9444x over previous
//
#include <hip/hip_runtime.h>
#include <cstdint>

#define EPS 1e-5f

typedef unsigned long long u64;
typedef unsigned int u32;
typedef unsigned short u16;
typedef unsigned char u8;

__device__ __forceinline__ int clampi(int v, int lo, int hi) {
    return v < lo ? lo : (v > hi ? hi : v);
}

// ======================= prep: fc1 repack (2048 blocks) + tiny packing (7 blocks) =======================
// Independent units -> one kernel, block-uniform branch.

__global__ __launch_bounds__(256) void prep_all(
    const float* __restrict__ fc1_w, u64* __restrict__ wp,
    const float* __restrict__ conv1_w, const float* __restrict__ conv2_w,
    const float* __restrict__ fc2_w,
    const float* __restrict__ g1, const float* __restrict__ b1,
    const float* __restrict__ m1, const float* __restrict__ v1,
    const float* __restrict__ g2, const float* __restrict__ b2,
    const float* __restrict__ m2, const float* __restrict__ v2,
    float* __restrict__ s1, u64* __restrict__ w2p, u64* __restrict__ w2pk,
    float4* __restrict__ bnc1, float4* __restrict__ bnc2)
{
    __shared__ float ls[3136];
    int bid = blockIdx.x;
    if (bid < 2048) {
        // fc1_w [2048,3136] (flat idx = c*49+p) -> wp[p*2048+o], bit c
        int o = bid;
        const float4* row4 = (const float4*)(fc1_w + o * 3136);
        for (int i = threadIdx.x; i < 784; i += 256)
            ((float4*)ls)[i] = row4[i];
        __syncthreads();
        int p = threadIdx.x;
        if (p < 49) {
            u64 word = 0;
            #pragma unroll
            for (int c = 0; c < 64; c++)
                word |= (u64)(ls[c * 49 + p] >= 0.f) << c;
            wp[p * 2048 + o] = word;
        }
    } else {
        int t = (bid - 2048) * 256 + threadIdx.x;   // 0..1791, active < 1600
        if (t < 576) {
            s1[t] = (conv1_w[t] >= 0.f) ? 1.f : -1.f;
        } else if (t < 1152) {
            int u = t - 576;
            int co = u / 9, tap = u % 9;
            u64 word = 0;
            for (int ci = 0; ci < 64; ci++)
                word |= (u64)(conv2_w[(co * 64 + ci) * 9 + tap] >= 0.f) << ci;
            w2p[u] = word;
        } else if (t < 1472) {
            int u = t - 1152;
            int o = u / 32, k = u % 32;
            u64 word = 0;
            for (int j = 0; j < 64; j++)
                word |= (u64)(fc2_w[o * 2048 + k * 64 + j] >= 0.f) << j;
            w2pk[u] = word;
        } else if (t < 1536) {
            int ch = t - 1472;
            bnc1[ch] = make_float4(m1[ch], g1[ch] / sqrtf(v1[ch] + EPS), b1[ch], 0.f);
        } else if (t < 1600) {
            int ch = t - 1536;
            bnc2[ch] = make_float4(m2[ch], g2[ch] / sqrtf(v2[ch] + EPS), b2[ch], 0.f);
        }
    }
}

// ---------- K1: conv1 + bn1 + sign + maxpool -> packed [B,14,14] ----------
// All 64 channels in one pass: patch loaded ONCE (was 4x), index math once,
// coalesced 8B/lane u64 store (was stride-8 u16). grid 1568 = 6 waves/SIMD.
// Weights + bn constants wave-uniform -> scalar loads; only 4 live fp accs.

__global__ __launch_bounds__(256) void k_conv1(
    const float* __restrict__ x, const float* __restrict__ s1,
    const float4* __restrict__ bnc1, u64* __restrict__ out1)
{
    int idx = blockIdx.x * 256 + threadIdx.x;  // b*196 + p, exactly 401408
    int b = idx / 196, p = idx % 196;
    int pi = p / 14, pj = p % 14;

    const float* xb = x + b * 784;
    int rr[4], cc[4];
    #pragma unroll
    for (int r = 0; r < 4; r++) rr[r] = clampi(2 * pi - 1 + r, 0, 27) * 28;
    #pragma unroll
    for (int c = 0; c < 4; c++) cc[c] = clampi(2 * pj - 1 + c, 0, 27);
    float patch[4][4];
    #pragma unroll
    for (int r = 0; r < 4; r++)
        #pragma unroll
        for (int c = 0; c < 4; c++)
            patch[r][c] = xb[rr[r] + cc[c]];

    u64 word = 0;
    #pragma unroll 4
    for (int ch = 0; ch < 64; ch++) {
        const float* w = s1 + ch * 9;           // wave-uniform -> s_load
        float v00 = 0.f, v01 = 0.f, v10 = 0.f, v11 = 0.f;
        #pragma unroll
        for (int ki = 0; ki < 3; ki++)
            #pragma unroll
            for (int kj = 0; kj < 3; kj++) {
                float ww = w[ki * 3 + kj];
                v00 += patch[ki][kj] * ww;
                v01 += patch[ki][kj + 1] * ww;
                v10 += patch[ki + 1][kj] * ww;
                v11 += patch[ki + 1][kj + 1] * ww;
            }
        float vmin = fminf(fminf(v00, v01), fminf(v10, v11));
        float vmax = fmaxf(fmaxf(v00, v01), fmaxf(v10, v11));
        float4 c4 = bnc1[ch];                   // wave-uniform -> s_load_dwordx4
        int bit = (((vmin - c4.x) * c4.y + c4.z) >= 0.f) |
                  (((vmax - c4.x) * c4.y + c4.z) >= 0.f);
        word |= (u64)bit << ch;
    }
    out1[idx] = word;
}

// ---------- K2: conv2 + bn2 + sign + maxpool -> packed [B,7,7] ----------
// 32 output channels per pass (was 8): 16xu64 window loaded 2x (was 8x).
// grid (392,2) = 784 blocks = 3 waves/SIMD; 16 independent loads/thread hide L2 latency.

__global__ __launch_bounds__(256) void k_conv2(
    const u64* __restrict__ in, const u64* __restrict__ w2p,
    const float4* __restrict__ bnc2, u64* __restrict__ out2)
{
    int g = blockIdx.y;                         // 0..1
    int base = g * 32;

    int idx = blockIdx.x * 256 + threadIdx.x;   // b*49 + p, exactly 100352
    int b = idx / 49, p = idx % 49;
    int pi = p / 7, pj = p % 7;

    const u64* ib = in + b * 196;
    int rr[4], cc[4];
    #pragma unroll
    for (int r = 0; r < 4; r++) rr[r] = clampi(2 * pi - 1 + r, 0, 13) * 14;
    #pragma unroll
    for (int c = 0; c < 4; c++) cc[c] = clampi(2 * pj - 1 + c, 0, 13);
    u64 a[4][4];
    #pragma unroll
    for (int r = 0; r < 4; r++)
        #pragma unroll
        for (int c = 0; c < 4; c++)
            a[r][c] = ib[rr[r] + cc[c]];

    u32 word = 0;
    #pragma unroll 4
    for (int co = 0; co < 32; co++) {
        const u64* w = w2p + (base + co) * 9;   // wave-uniform -> s_load
        int s00 = 0, s01 = 0, s10 = 0, s11 = 0;
        #pragma unroll
        for (int ki = 0; ki < 3; ki++)
            #pragma unroll
            for (int kj = 0; kj < 3; kj++) {
                u64 ww = w[ki * 3 + kj];
                s00 += __popcll(a[ki][kj] ^ ww);
                s01 += __popcll(a[ki][kj + 1] ^ ww);
                s10 += __popcll(a[ki + 1][kj] ^ ww);
                s11 += __popcll(a[ki + 1][kj + 1] ^ ww);
            }
        int smin = min(min(s00, s01), min(s10, s11));
        int smax = max(max(s00, s01), max(s10, s11));
        float4 c4 = bnc2[base + co];
        int bit = (((float)(576 - 2 * smin) - c4.x) * c4.y + c4.z >= 0.f) |
                  (((float)(576 - 2 * smax) - c4.x) * c4.y + c4.z >= 0.f);
        word |= (u32)bit << co;
    }
    ((u32*)out2)[idx * 2 + g] = word;           // little-endian u64 halves
}

// ---------- K3: fc1 + bn3 + sign -> packed [B,32] (unchanged, proven) ----------

#define NB 8

__global__ __launch_bounds__(256) void k_fc1(
    const u64* __restrict__ act, const u64* __restrict__ wp,
    const float* __restrict__ g, const float* __restrict__ bt,
    const float* __restrict__ mn, const float* __restrict__ vr,
    u64* __restrict__ out3)
{
    int tid = threadIdx.x;
    int btile = blockIdx.x >> 3;               // 256 tiles of NB batches
    int otile = blockIdx.x & 7;                // 8 tiles of 256 outputs
    int b0 = btile * NB;
    int o = otile * 256 + tid;
    const u64* ab = act + b0 * 49;

    int sums[NB];
    #pragma unroll
    for (int i = 0; i < NB; i++) sums[i] = 0;

    for (int p = 0; p < 49; p++) {
        u64 w = wp[p * 2048 + o];
        #pragma unroll
        for (int bb = 0; bb < NB; bb++)
            sums[bb] += __popcll(ab[bb * 49 + p] ^ w);   // ab idx uniform -> s_load
    }

    float iv = g[o] / sqrtf(vr[o] + EPS);
    float m = mn[o], be = bt[o];
    #pragma unroll
    for (int bb = 0; bb < NB; bb++) {
        float y = ((float)(3136 - 2 * sums[bb]) - m) * iv + be;
        u64 ball = __ballot(y >= 0.f);
        if ((tid & 63) == 0) out3[(b0 + bb) * 32 + (o >> 6)] = ball;
    }
}

// ---------- K4: fc2 + scale (unchanged, proven) ----------

__global__ void k_fc2(const u64* __restrict__ act, const u64* __restrict__ w2,
                      const float* __restrict__ scale, float* __restrict__ out)
{
    int idx = blockIdx.x * 256 + threadIdx.x;  // b*16 + o (o<10 active)
    if (idx >= 2048 * 16) return;
    int b = idx >> 4, o = idx & 15;
    if (o >= 10) return;
    int s = 0;
    #pragma unroll
    for (int k = 0; k < 32; k++)
        s += __popcll(act[b * 32 + k] ^ w2[o * 32 + k]);
    out[b * 10 + o] = scale[0] * (float)(2048 - 2 * s);
}

// ======================= launch =======================

extern "C" void kernel_launch(void* const* d_in, const int* in_sizes, int n_in,
                              void* d_out, int out_size, void* d_ws, size_t ws_size,
                              hipStream_t stream) {
    const float* x        = (const float*)d_in[0];
    const float* conv1_w  = (const float*)d_in[1];
    const float* bn1_g    = (const float*)d_in[2];
    const float* bn1_b    = (const float*)d_in[3];
    const float* bn1_m    = (const float*)d_in[4];
    const float* bn1_v    = (const float*)d_in[5];
    const float* conv2_w  = (const float*)d_in[6];
    const float* bn2_g    = (const float*)d_in[7];
    const float* bn2_b    = (const float*)d_in[8];
    const float* bn2_m    = (const float*)d_in[9];
    const float* bn2_v    = (const float*)d_in[10];
    const float* fc1_w    = (const float*)d_in[11];
    const float* bn3_g    = (const float*)d_in[12];
    const float* bn3_b    = (const float*)d_in[13];
    const float* bn3_m    = (const float*)d_in[14];
    const float* bn3_v    = (const float*)d_in[15];
    const float* fc2_w    = (const float*)d_in[16];
    const float* scale    = (const float*)d_in[17];
    float* out = (float*)d_out;

    char* ws = (char*)d_ws;
    float*  s1   = (float*) (ws + 0);          //   2304 B
    u64*    w2p  = (u64*)   (ws + 2560);       //   4608 B (ends 7168)
    float4* bnc1 = (float4*)(ws + 7168);       //   1024 B (ends 8192)
    u64*    wp   = (u64*)   (ws + 8192);       // 802816 B (ends 811008)
    u64*    w2pk = (u64*)   (ws + 811008);     //   2560 B (ends 813568)
    float4* bnc2 = (float4*)(ws + 813568);     //   1024 B (ends 814592)
    u64*    out1 = (u64*)   (ws + 819200);     // 3211264 B (ends 4030464)
    u64*    out2 = (u64*)   (ws + 4030464);    // 802816 B (ends 4833280)
    u64*    out3 = (u64*)   (ws + 4833280);    // 524288 B (ends 5357568)

    hipLaunchKernelGGL(prep_all, dim3(2055), dim3(256), 0, stream,
                       fc1_w, wp, conv1_w, conv2_w, fc2_w,
                       bn1_g, bn1_b, bn1_m, bn1_v,
                       bn2_g, bn2_b, bn2_m, bn2_v,
                       s1, w2p, w2pk, bnc1, bnc2);

    hipLaunchKernelGGL(k_conv1, dim3(1568), dim3(256), 0, stream,
                       x, s1, bnc1, out1);
    hipLaunchKernelGGL(k_conv2, dim3(392, 2), dim3(256), 0, stream,
                       out1, w2p, bnc2, out2);
    hipLaunchKernelGGL(k_fc1, dim3(2048), dim3(256), 0, stream,
                       out2, wp, bn3_g, bn3_b, bn3_m, bn3_v, out3);
    hipLaunchKernelGGL(k_fc2, dim3(128), dim3(256), 0, stream,
                       out3, w2pk, scale, out);
}

// Round 4
// 205.078 us; speedup vs baseline: 3.4019x; 1.1554x over previous
//
#include <hip/hip_runtime.h>
#include <cstdint>

#define EPS 1e-5f

typedef unsigned long long u64;
typedef unsigned int u32;
typedef unsigned short u16;
typedef unsigned char u8;
typedef float v2f __attribute__((ext_vector_type(2)));

__device__ __forceinline__ int clampi(int v, int lo, int hi) {
    return v < lo ? lo : (v > hi ? hi : v);
}

// exact elementwise helpers (packed when HW/compiler support, scalar-exact fallback)
__device__ __forceinline__ v2f v2_fma(v2f a, v2f b, v2f c) {
#if __has_builtin(__builtin_elementwise_fma)
    return __builtin_elementwise_fma(a, b, c);
#else
    v2f r; r.x = __builtin_fmaf(a.x, b.x, c.x); r.y = __builtin_fmaf(a.y, b.y, c.y); return r;
#endif
}
__device__ __forceinline__ v2f v2_min(v2f a, v2f b) {
#if __has_builtin(__builtin_elementwise_min)
    return __builtin_elementwise_min(a, b);
#else
    v2f r; r.x = fminf(a.x, b.x); r.y = fminf(a.y, b.y); return r;
#endif
}
__device__ __forceinline__ v2f v2_max(v2f a, v2f b) {
#if __has_builtin(__builtin_elementwise_max)
    return __builtin_elementwise_max(a, b);
#else
    v2f r; r.x = fmaxf(a.x, b.x); r.y = fmaxf(a.y, b.y); return r;
#endif
}

// ======================= prep: fc1 repack (2048 blocks) + tiny packing (7 blocks) =======================

__global__ __launch_bounds__(256) void prep_all(
    const float* __restrict__ fc1_w, u64* __restrict__ wp,
    const float* __restrict__ conv1_w, const float* __restrict__ conv2_w,
    const float* __restrict__ fc2_w,
    const float* __restrict__ g1, const float* __restrict__ b1,
    const float* __restrict__ m1, const float* __restrict__ v1,
    const float* __restrict__ g2, const float* __restrict__ b2,
    const float* __restrict__ m2, const float* __restrict__ v2,
    v2f* __restrict__ s1d, u64* __restrict__ w2p, u64* __restrict__ w2pk,
    float4* __restrict__ bnc1, float4* __restrict__ bnc2)
{
    __shared__ float ls[3136];
    int bid = blockIdx.x;
    if (bid < 2048) {
        // fc1_w [2048,3136] (flat idx = c*49+p) -> wp[p*2048+o], bit c
        int o = bid;
        const float4* row4 = (const float4*)(fc1_w + o * 3136);
        for (int i = threadIdx.x; i < 784; i += 256)
            ((float4*)ls)[i] = row4[i];
        __syncthreads();
        int p = threadIdx.x;
        if (p < 49) {
            u64 word = 0;
            #pragma unroll
            for (int c = 0; c < 64; c++)
                word |= (u64)(ls[c * 49 + p] >= 0.f) << c;
            wp[p * 2048 + o] = word;
        }
    } else {
        int t = (bid - 2048) * 256 + threadIdx.x;   // 0..1791, active < 1600
        if (t < 576) {
            float s = (conv1_w[t] >= 0.f) ? 1.f : -1.f;
            v2f d; d.x = s; d.y = s;
            s1d[t] = d;                             // duplicated for v_pk_fma
        } else if (t < 1152) {
            int u = t - 576;
            int co = u / 9, tap = u % 9;
            u64 word = 0;
            for (int ci = 0; ci < 64; ci++)
                word |= (u64)(conv2_w[(co * 64 + ci) * 9 + tap] >= 0.f) << ci;
            w2p[u] = word;
        } else if (t < 1472) {
            int u = t - 1152;
            int o = u / 32, k = u % 32;
            u64 word = 0;
            for (int j = 0; j < 64; j++)
                word |= (u64)(fc2_w[o * 2048 + k * 64 + j] >= 0.f) << j;
            w2pk[u] = word;
        } else if (t < 1536) {
            int ch = t - 1472;
            bnc1[ch] = make_float4(m1[ch], g1[ch] / sqrtf(v1[ch] + EPS), b1[ch], 0.f);
        } else if (t < 1600) {
            int ch = t - 1536;
            bnc2[ch] = make_float4(m2[ch], g2[ch] / sqrtf(v2[ch] + EPS), b2[ch], 0.f);
        }
    }
}

// ---------- K1: conv1 + bn1 + sign + maxpool -> packed [B,14,14] ----------
// Round-0 grid (1568,4): 16 channels/thread, 25088 waves (~24/SIMD) - proven TLP.
// NEW: packed-fp32 core. Accumulate {v00,v01} and {v10,v11} as float2 via
// v_pk_fma_f32 (weights pre-duplicated {w,w} -> one s_load_dwordx2, SGPR-pair src).
// 36 scalar FMA/ch -> 18 pk FMA/ch. min/max reassociation + fma rounding are
// bit-exact vs the scalar version (absmax must stay 0).

__global__ __launch_bounds__(256) void k_conv1(
    const float* __restrict__ x, const v2f* __restrict__ s1d,
    const float4* __restrict__ bnc1, u64* __restrict__ out1)
{
    int tid = threadIdx.x;
    int g = blockIdx.y;
    int base = g * 16;

    int idx = blockIdx.x * 256 + tid;          // b*196 + p, exactly 401408
    int b = idx / 196, p = idx % 196;
    int pi = p / 14, pj = p % 14;

    const float* xb = x + b * 784;
    int rr[4], cc[4];
    #pragma unroll
    for (int r = 0; r < 4; r++) rr[r] = clampi(2 * pi - 1 + r, 0, 27) * 28;
    #pragma unroll
    for (int c = 0; c < 4; c++) cc[c] = clampi(2 * pj - 1 + c, 0, 27);
    float patch[4][4];
    #pragma unroll
    for (int r = 0; r < 4; r++)
        #pragma unroll
        for (int c = 0; c < 4; c++)
            patch[r][c] = xb[rr[r] + cc[c]];

    // adjacent-column pairs, shared by all 16 channels
    v2f pp[4][3];
    #pragma unroll
    for (int r = 0; r < 4; r++)
        #pragma unroll
        for (int j = 0; j < 3; j++) {
            v2f t; t.x = patch[r][j]; t.y = patch[r][j + 1];
            pp[r][j] = t;
        }

    u32 word = 0;
    #pragma unroll 4
    for (int ch = 0; ch < 16; ch++) {
        const v2f* w = s1d + (base + ch) * 9;   // wave-uniform -> s_load_dwordx2
        v2f a01 = 0.f, a23 = 0.f;               // {v00,v01}, {v10,v11}
        #pragma unroll
        for (int ki = 0; ki < 3; ki++)
            #pragma unroll
            for (int kj = 0; kj < 3; kj++) {
                v2f ww = w[ki * 3 + kj];
                a01 = v2_fma(pp[ki][kj],     ww, a01);
                a23 = v2_fma(pp[ki + 1][kj], ww, a23);
            }
        v2f mn = v2_min(a01, a23);
        v2f mx = v2_max(a01, a23);
        float vmin = fminf(mn.x, mn.y);
        float vmax = fmaxf(mx.x, mx.y);
        float4 c4 = bnc1[base + ch];            // wave-uniform -> s_load_dwordx4
        int bit = (((vmin - c4.x) * c4.y + c4.z) >= 0.f) |
                  (((vmax - c4.x) * c4.y + c4.z) >= 0.f);
        word |= (u32)bit << ch;
    }
    ((u16*)out1)[idx * 4 + g] = (u16)word;      // little-endian u64 quarters
}

// ---------- K2: conv2 + bn2 + sign + maxpool -> packed [B,7,7] ----------
// Round-0 proven config: grid (392,8), 8 out-channels/thread, 12544 waves (~12/SIMD).

__global__ __launch_bounds__(256) void k_conv2(
    const u64* __restrict__ in, const u64* __restrict__ w2p,
    const float4* __restrict__ bnc2, u64* __restrict__ out2)
{
    int tid = threadIdx.x;
    int g = blockIdx.y;
    int base = g * 8;

    int idx = blockIdx.x * 256 + tid;          // b*49 + p, exactly 100352
    int b = idx / 49, p = idx % 49;
    int pi = p / 7, pj = p % 7;

    const u64* ib = in + b * 196;
    int rr[4], cc[4];
    #pragma unroll
    for (int r = 0; r < 4; r++) rr[r] = clampi(2 * pi - 1 + r, 0, 13) * 14;
    #pragma unroll
    for (int c = 0; c < 4; c++) cc[c] = clampi(2 * pj - 1 + c, 0, 13);
    u64 a[4][4];
    #pragma unroll
    for (int r = 0; r < 4; r++)
        #pragma unroll
        for (int c = 0; c < 4; c++)
            a[r][c] = ib[rr[r] + cc[c]];

    u32 word = 0;
    #pragma unroll
    for (int co = 0; co < 8; co++) {
        const u64* w = w2p + (base + co) * 9;   // wave-uniform -> s_load
        int s00 = 0, s01 = 0, s10 = 0, s11 = 0;
        #pragma unroll
        for (int ki = 0; ki < 3; ki++)
            #pragma unroll
            for (int kj = 0; kj < 3; kj++) {
                u64 ww = w[ki * 3 + kj];
                s00 += __popcll(a[ki][kj] ^ ww);
                s01 += __popcll(a[ki][kj + 1] ^ ww);
                s10 += __popcll(a[ki + 1][kj] ^ ww);
                s11 += __popcll(a[ki + 1][kj + 1] ^ ww);
            }
        int smin = min(min(s00, s01), min(s10, s11));
        int smax = max(max(s00, s01), max(s10, s11));
        float4 c4 = bnc2[base + co];
        int bit = (((float)(576 - 2 * smin) - c4.x) * c4.y + c4.z >= 0.f) |
                  (((float)(576 - 2 * smax) - c4.x) * c4.y + c4.z >= 0.f);
        word |= (u32)bit << co;
    }
    ((u8*)out2)[idx * 8 + g] = (u8)word;        // little-endian u64 bytes
}

// ---------- K3: fc1 + bn3 + sign -> packed [B,32] (unchanged, proven) ----------

#define NB 8

__global__ __launch_bounds__(256) void k_fc1(
    const u64* __restrict__ act, const u64* __restrict__ wp,
    const float* __restrict__ g, const float* __restrict__ bt,
    const float* __restrict__ mn, const float* __restrict__ vr,
    u64* __restrict__ out3)
{
    int tid = threadIdx.x;
    int btile = blockIdx.x >> 3;               // 256 tiles of NB batches
    int otile = blockIdx.x & 7;                // 8 tiles of 256 outputs
    int b0 = btile * NB;
    int o = otile * 256 + tid;
    const u64* ab = act + b0 * 49;

    int sums[NB];
    #pragma unroll
    for (int i = 0; i < NB; i++) sums[i] = 0;

    for (int p = 0; p < 49; p++) {
        u64 w = wp[p * 2048 + o];
        #pragma unroll
        for (int bb = 0; bb < NB; bb++)
            sums[bb] += __popcll(ab[bb * 49 + p] ^ w);   // ab idx uniform -> s_load
    }

    float iv = g[o] / sqrtf(vr[o] + EPS);
    float m = mn[o], be = bt[o];
    #pragma unroll
    for (int bb = 0; bb < NB; bb++) {
        float y = ((float)(3136 - 2 * sums[bb]) - m) * iv + be;
        u64 ball = __ballot(y >= 0.f);
        if ((tid & 63) == 0) out3[(b0 + bb) * 32 + (o >> 6)] = ball;
    }
}

// ---------- K4: fc2 + scale (unchanged, proven) ----------

__global__ void k_fc2(const u64* __restrict__ act, const u64* __restrict__ w2,
                      const float* __restrict__ scale, float* __restrict__ out)
{
    int idx = blockIdx.x * 256 + threadIdx.x;  // b*16 + o (o<10 active)
    if (idx >= 2048 * 16) return;
    int b = idx >> 4, o = idx & 15;
    if (o >= 10) return;
    int s = 0;
    #pragma unroll
    for (int k = 0; k < 32; k++)
        s += __popcll(act[b * 32 + k] ^ w2[o * 32 + k]);
    out[b * 10 + o] = scale[0] * (float)(2048 - 2 * s);
}

// ======================= launch =======================

extern "C" void kernel_launch(void* const* d_in, const int* in_sizes, int n_in,
                              void* d_out, int out_size, void* d_ws, size_t ws_size,
                              hipStream_t stream) {
    const float* x        = (const float*)d_in[0];
    const float* conv1_w  = (const float*)d_in[1];
    const float* bn1_g    = (const float*)d_in[2];
    const float* bn1_b    = (const float*)d_in[3];
    const float* bn1_m    = (const float*)d_in[4];
    const float* bn1_v    = (const float*)d_in[5];
    const float* conv2_w  = (const float*)d_in[6];
    const float* bn2_g    = (const float*)d_in[7];
    const float* bn2_b    = (const float*)d_in[8];
    const float* bn2_m    = (const float*)d_in[9];
    const float* bn2_v    = (const float*)d_in[10];
    const float* fc1_w    = (const float*)d_in[11];
    const float* bn3_g    = (const float*)d_in[12];
    const float* bn3_b    = (const float*)d_in[13];
    const float* bn3_m    = (const float*)d_in[14];
    const float* bn3_v    = (const float*)d_in[15];
    const float* fc2_w    = (const float*)d_in[16];
    const float* scale    = (const float*)d_in[17];
    float* out = (float*)d_out;

    char* ws = (char*)d_ws;
    v2f*    s1d  = (v2f*)   (ws + 0);          //   4608 B (ends 4608)
    u64*    w2p  = (u64*)   (ws + 4608);       //   4608 B (ends 9216)
    float4* bnc1 = (float4*)(ws + 9216);       //   1024 B (ends 10240)
    float4* bnc2 = (float4*)(ws + 10240);      //   1024 B (ends 11264)
    u64*    w2pk = (u64*)   (ws + 11264);      //   2560 B (ends 13824)
    u64*    wp   = (u64*)   (ws + 16384);      // 802816 B (ends 819200)
    u64*    out1 = (u64*)   (ws + 819200);     // 3211264 B (ends 4030464)
    u64*    out2 = (u64*)   (ws + 4030464);    // 802816 B (ends 4833280)
    u64*    out3 = (u64*)   (ws + 4833280);    // 524288 B (ends 5357568)

    hipLaunchKernelGGL(prep_all, dim3(2055), dim3(256), 0, stream,
                       fc1_w, wp, conv1_w, conv2_w, fc2_w,
                       bn1_g, bn1_b, bn1_m, bn1_v,
                       bn2_g, bn2_b, bn2_m, bn2_v,
                       s1d, w2p, w2pk, bnc1, bnc2);

    hipLaunchKernelGGL(k_conv1, dim3(1568, 4), dim3(256), 0, stream,
                       x, s1d, bnc1, out1);
    hipLaunchKernelGGL(k_conv2, dim3(392, 8), dim3(256), 0, stream,
                       out1, w2p, bnc2, out2);
    hipLaunchKernelGGL(k_fc1, dim3(2048), dim3(256), 0, stream,
                       out2, wp, bn3_g, bn3_b, bn3_m, bn3_v, out3);
    hipLaunchKernelGGL(k_fc2, dim3(128), dim3(256), 0, stream,
                       out3, w2pk, scale, out);
}